// Round 3
// baseline (124.343 us; speedup 1.0000x reference)
//
#include <hip/hip_runtime.h>

// ContrastiveEmbeddingLoss, N=8192, D=128, C=100, margin=1.
// loss = [ sum_{y_i!=y_j} d_ij + N*margin + sum_{same,i!=j} max(margin-d_ij,0) ] / N^2
//   sum_all d  = 2N*SQ - 2||S||^2
//   sum_same d = sum_c ( 2 n_c SQ_c - 2 SS_c ),  SS_c = sum_{a,b in c} x_a.x_b
// SS_c is exactly the sum of all per-class Gram entries, which the hinge MFMA
// already computes -> no per-class column sums needed. Only same-class pairs
// (~N^2/100) need explicit d.
//
// 3 graph nodes: memset(404B) -> scan (class-grouped fp16 rows + global stats)
// -> gram (MFMA hinge straight from global, last block finalizes via atomic).

#define N_ROWS 8192
#define DIM    128
#define NCLS   100
#define CAP    224            // Binom(8192,0.01): mean 82, sd 9 -> +15 sigma
#define SB     256            // scan blocks
#define SROWS  (N_ROWS / SB)  // 32 rows per scan block

typedef _Float16 half8  __attribute__((ext_vector_type(8)));
typedef _Float16 half4v __attribute__((ext_vector_type(4)));
typedef float    float4v __attribute__((ext_vector_type(4)));

// ---------------- Kernel 1: single coalesced pass over x ----------------
// Writes: gh[c][rank][128] fp16 rows (class-grouped), sqg[c][rank] sqnorms,
// cnt[c], colpart[SB][128] column-sum partials, sqpart[SB] SQ partials.
__global__ __launch_bounds__(256) void scan_kernel(
    const float* __restrict__ x, const int* __restrict__ y,
    _Float16* __restrict__ gh, float* __restrict__ sqg, int* __restrict__ cnt,
    float* __restrict__ colpart, float* __restrict__ sqpart)
{
    const int b = blockIdx.x, tid = threadIdx.x;
    const int l = tid & 31, g = tid >> 5;      // 32 lanes per row, 8 rows/pass
    const float4* x4 = (const float4*)x;
    float4 ca = make_float4(0.f, 0.f, 0.f, 0.f);
    __shared__ float  sqred[SROWS];
    __shared__ float4 colred[256];

    #pragma unroll
    for (int pass = 0; pass < SROWS / 8; ++pass) {
        const int r = b * SROWS + pass * 8 + g;
        float4 v = x4[r * 32 + l];             // fully coalesced
        ca.x += v.x; ca.y += v.y; ca.z += v.z; ca.w += v.w;
        float s = v.x*v.x + v.y*v.y + v.z*v.z + v.w*v.w;
        s += __shfl_xor(s, 1);  s += __shfl_xor(s, 2);  s += __shfl_xor(s, 4);
        s += __shfl_xor(s, 8);  s += __shfl_xor(s, 16);   // full row sqnorm
        const int c = y[r];                    // same addr in group -> broadcast
        int p = 0;
        if (l == 0) p = atomicAdd(&cnt[c], 1);
        p = __shfl(p, 0, 32);
        if (p < CAP) {                         // never false in practice
            half4v h;
            h[0] = (_Float16)v.x; h[1] = (_Float16)v.y;
            h[2] = (_Float16)v.z; h[3] = (_Float16)v.w;
            *(half4v*)(gh + (size_t)(c * CAP + p) * DIM + l * 4) = h;
            if (l == 0) sqg[c * CAP + p] = s;
        }
        if (l == 0) sqred[pass * 8 + g] = s;
    }
    colred[tid] = ca;
    __syncthreads();
    if (tid < 32) {
        float4 a = colred[tid];
        #pragma unroll
        for (int gg = 1; gg < 8; ++gg) {
            float4 t = colred[tid + 32 * gg];
            a.x += t.x; a.y += t.y; a.z += t.z; a.w += t.w;
        }
        ((float4*)colpart)[b * 32 + tid] = a;  // cols 4*tid..4*tid+3
        float s2 = sqred[tid];
        s2 += __shfl_xor(s2, 1);  s2 += __shfl_xor(s2, 2);  s2 += __shfl_xor(s2, 4);
        s2 += __shfl_xor(s2, 8);  s2 += __shfl_xor(s2, 16);
        if (tid == 0) sqpart[b] = s2;
    }
}

// ---------------- Kernel 2: per-class MFMA Gram hinge + fused finalize ----
__global__ __launch_bounds__(256) void gram_kernel(
    const _Float16* __restrict__ gh, const float* __restrict__ sqg,
    const int* __restrict__ cnt,
    const float* __restrict__ colpart, const float* __restrict__ sqpart,
    float* __restrict__ Hc, float* __restrict__ SSc, float* __restrict__ NSQc,
    int* __restrict__ done, float* __restrict__ out)
{
    const int c = blockIdx.x, tid = threadIdx.x;
    __shared__ float sqm[CAP];
    __shared__ float wred[8];     // per-wave hinge / dotsum partials
    __shared__ float qred[4];     // per-wave sqnorm-sum partials
    __shared__ int   lastFlag;

    const int mtrue = cnt[c];
    const int m = mtrue < CAP ? mtrue : CAP;
    const int ntiles = (m + 15) >> 4;

    if (tid < CAP) sqm[tid] = (tid < m) ? sqg[c * CAP + tid] : 0.f;
    float q0 = (tid < m) ? sqg[c * CAP + tid] : 0.f;

    const int wave = tid >> 6, lane = tid & 63;
    const int lr = lane & 15, q = lane >> 4;
    {   // per-wave reduce of q0 (no LDS dependency yet)
        #pragma unroll
        for (int off = 32; off > 0; off >>= 1) q0 += __shfl_xor(q0, off);
        if (lane == 0) qred[wave] = q0;
    }
    __syncthreads();   // sqm + qred ready

    // Upper-triangle tile pairs; fragments straight from global grouped rows.
    float hacc = 0.f, dsum = 0.f;
    {
        const _Float16* base = gh + (size_t)c * CAP * DIM;
        const int ntp = ntiles * (ntiles + 1) / 2;
        const half8 z = {0, 0, 0, 0, 0, 0, 0, 0};
        for (int tp = wave; tp < ntp; tp += 4) {
            int ta = 0, rem = tp;
            while (rem >= ntiles - ta) { rem -= ntiles - ta; ++ta; }
            const int tb = ta + rem;
            const int ra = ta * 16 + lr, rb = tb * 16 + lr;
            const half8* ap = (const half8*)(base + ra * DIM + q * 8);
            const half8* bp = (const half8*)(base + rb * DIM + q * 8);
            const bool va = ra < m, vb = rb < m;
            float4v acc = {0.f, 0.f, 0.f, 0.f};
            #pragma unroll
            for (int kb = 0; kb < 4; ++kb) {   // +32 halves per K block
                half8 af = va ? ap[kb * 4] : z;
                half8 bf = vb ? bp[kb * 4] : z;
                acc = __builtin_amdgcn_mfma_f32_16x16x32_f16(af, bf, acc, 0, 0, 0);
            }
            const float w = (ta == tb) ? 1.f : 2.f;
            #pragma unroll
            for (int i = 0; i < 4; ++i) {
                const int a  = ta * 16 + q * 4 + i;   // C/D: row = quad*4 + reg
                const int bb = tb * 16 + lr;          //      col = lane & 15
                if (a < m && bb < m) {
                    const float dot = acc[i];
                    dsum += w * dot;                  // includes diagonal a==bb
                    if (a != bb) {
                        float d = fmaxf(sqm[a] + sqm[bb] - 2.f * dot, 0.f);
                        hacc += w * fmaxf(1.f - d, 0.f);
                    }
                }
            }
        }
    }
    #pragma unroll
    for (int off = 32; off > 0; off >>= 1) {
        hacc += __shfl_xor(hacc, off);
        dsum += __shfl_xor(dsum, off);
    }
    if (lane == 0) { wred[wave] = hacc; wred[4 + wave] = dsum; }
    __syncthreads();
    if (tid == 0) {
        Hc[c]   = wred[0] + wred[1] + wred[2] + wred[3];
        SSc[c]  = wred[4] + wred[5] + wred[6] + wred[7];
        NSQc[c] = (float)mtrue * (qred[0] + qred[1] + qred[2] + qred[3]);
        __threadfence();                       // release per-class results
        int p = atomicAdd(done, 1);
        lastFlag = (p == NCLS - 1);
    }
    __syncthreads();
    if (!lastFlag) return;

    // ---------------- fused finalize (last-arriving block only) ----------
    __threadfence();                           // acquire other blocks' writes
    __shared__ float  scol[DIM];
    __shared__ double dred[256];
    {
        const int d = tid & 127, h = tid >> 7; // 2 threads per column
        float s = 0.f;
        for (int b = h; b < SB; b += 2) s += colpart[b * DIM + d];
        if (h == 0) scol[d] = s;
        __syncthreads();
        if (h == 1) scol[d] += s;
        __syncthreads();
    }
    // Everything combines linearly: one double reduction.
    const double Nf = (double)N_ROWS;
    double contrib = 0.0;
    if (tid < DIM)  { double v = scol[tid]; contrib -= 2.0 * v * v; }       // -2||S||^2
    contrib += 2.0 * Nf * (double)sqpart[tid];                              // +2N*SQ (tid<SB==256)
    if (tid < NCLS) {
        contrib -= 2.0 * (double)NSQc[tid];                                 // -2 n_c SQ_c
        contrib += 2.0 * (double)SSc[tid];                                  // +2 SS_c
        contrib += (double)Hc[tid];                                         // + hinge
    }
    dred[tid] = contrib;
    __syncthreads();
    for (int s = 128; s > 0; s >>= 1) {
        if (tid < s) dred[tid] += dred[tid + s];
        __syncthreads();
    }
    if (tid == 0) out[0] = (float)((dred[0] + Nf * 1.0 /*N*margin*/) / (Nf * Nf));
}

extern "C" void kernel_launch(void* const* d_in, const int* in_sizes, int n_in,
                              void* d_out, int out_size, void* d_ws, size_t ws_size,
                              hipStream_t stream) {
    const float* x = (const float*)d_in[0];
    const int*   y = (const int*)d_in[1];

    _Float16* gh   = (_Float16*)d_ws;                 // 100*224*128 fp16 = 5.73 MB
    float* sqg     = (float*)(gh + (size_t)NCLS * CAP * DIM); // 100*224
    float* colpart = sqg + NCLS * CAP;                // SB*128
    float* sqpart  = colpart + SB * DIM;              // SB
    float* Hc      = sqpart + SB;                     // 100
    float* SSc     = Hc + NCLS;                       // 100
    float* NSQc    = SSc + NCLS;                      // 100
    int*   cnt     = (int*)(NSQc + NCLS);             // 100  (memset)
    int*   done    = cnt + NCLS;                      // 1    (memset)
    // ~6 MB of ws; only cnt+done (404 B) need zeroing.

    hipMemsetAsync(cnt, 0, (NCLS + 1) * sizeof(int), stream);
    scan_kernel<<<SB,   256, 0, stream>>>(x, y, gh, sqg, cnt, colpart, sqpart);
    gram_kernel<<<NCLS, 256, 0, stream>>>(gh, sqg, cnt, colpart, sqpart,
                                          Hc, SSc, NSQc, done, (float*)d_out);
}

// Round 4
// 110.646 us; speedup vs baseline: 1.1238x; 1.1238x over previous
//
#include <hip/hip_runtime.h>

// ContrastiveEmbeddingLoss, N=8192, D=128, C=100, margin=1.
// loss = [ sum_{y_i!=y_j} d_ij + N*margin + sum_{same,i!=j} max(margin-d_ij,0) ] / N^2
//   dissim = 2*sum_c SQ_c*(N - n_c) - 2*||S||^2 + 2*SSsum,
//     SQ_c = sum_{i in c}||x_i||^2,  S = sum_i x_i,  SSsum = sum_c sum_{a,b in c} x_a.x_b
// Only same-class pairs (~N^2/100) need explicit d -> per-class fp16 MFMA Gram.
//
// 3 graph nodes: memset(1.3KB) -> scan (class-grouped fp16 rows + atomic stats)
// -> gram (400 blocks, MFMA hinge from global; last block finalizes via atomic).

#define N_ROWS 8192
#define DIM    128
#define NCLS   100
#define CAP    224            // Binom(8192,0.01): mean 82, sd 9 -> +15 sigma
#define SB     256            // scan blocks
#define SROWS  (N_ROWS / SB)  // 32 rows per scan block
#define GBPC   4              // gram blocks per class
#define GRAMB  (NCLS * GBPC)  // 400

typedef _Float16 half8  __attribute__((ext_vector_type(8)));
typedef _Float16 half4v __attribute__((ext_vector_type(4)));
typedef float    float4v __attribute__((ext_vector_type(4)));

// ---------------- Kernel 1: single coalesced pass over x ----------------
// gh[c][rank][128] fp16 rows (class-grouped), sqg[c][rank], cnt[c],
// Scol[128] (atomic col sums), SQc[100] (atomic per-class sqnorm sums).
__global__ __launch_bounds__(256) void scan_kernel(
    const float* __restrict__ x, const int* __restrict__ y,
    _Float16* __restrict__ gh, float* __restrict__ sqg, int* __restrict__ cnt,
    float* __restrict__ Scol, float* __restrict__ SQc)
{
    const int b = blockIdx.x, tid = threadIdx.x;
    const int l = tid & 31, g = tid >> 5;      // 32 lanes per row, 8 rows/pass
    const float4* x4 = (const float4*)x;
    float4 ca = make_float4(0.f, 0.f, 0.f, 0.f);
    __shared__ float4 colred[256];

    #pragma unroll
    for (int pass = 0; pass < SROWS / 8; ++pass) {
        const int r = b * SROWS + pass * 8 + g;
        float4 v = x4[r * 32 + l];             // fully coalesced
        ca.x += v.x; ca.y += v.y; ca.z += v.z; ca.w += v.w;
        float s = v.x*v.x + v.y*v.y + v.z*v.z + v.w*v.w;
        s += __shfl_xor(s, 1);  s += __shfl_xor(s, 2);  s += __shfl_xor(s, 4);
        s += __shfl_xor(s, 8);  s += __shfl_xor(s, 16);   // full row sqnorm
        const int c = y[r];
        int p = 0;
        if (l == 0) p = atomicAdd(&cnt[c], 1);
        p = __shfl(p, 0, 32);
        if (p < CAP) {                         // never false in practice
            half4v h;
            h[0] = (_Float16)v.x; h[1] = (_Float16)v.y;
            h[2] = (_Float16)v.z; h[3] = (_Float16)v.w;
            *(half4v*)(gh + (size_t)(c * CAP + p) * DIM + l * 4) = h;
            if (l == 0) sqg[c * CAP + p] = s;
        }
        if (l == 0) atomicAdd(&SQc[c], s);
    }
    colred[tid] = ca;
    __syncthreads();
    if (tid < 32) {
        float4 a = colred[tid];
        #pragma unroll
        for (int gg = 1; gg < 8; ++gg) {
            float4 t = colred[tid + 32 * gg];
            a.x += t.x; a.y += t.y; a.z += t.z; a.w += t.w;
        }
        atomicAdd(&Scol[4 * tid + 0], a.x);
        atomicAdd(&Scol[4 * tid + 1], a.y);
        atomicAdd(&Scol[4 * tid + 2], a.z);
        atomicAdd(&Scol[4 * tid + 3], a.w);
    }
}

// ------- Kernel 2: per-class MFMA Gram hinge (4 blocks/class) + finalize ----
__global__ __launch_bounds__(256) void gram_kernel(
    const _Float16* __restrict__ gh, const float* __restrict__ sqg,
    const int* __restrict__ cnt, const float* __restrict__ Scol,
    const float* __restrict__ SQc,
    float* __restrict__ Hsum, float* __restrict__ SSsum,
    int* __restrict__ done, float* __restrict__ out)
{
    const int c = blockIdx.x >> 2, qq = blockIdx.x & 3, tid = threadIdx.x;
    __shared__ float sqm[CAP];
    __shared__ float wred[8];
    __shared__ int   lastFlag;

    const int mtrue = cnt[c];
    const int m = mtrue < CAP ? mtrue : CAP;
    const int ntiles = (m + 15) >> 4;
    const int ntp = ntiles * (ntiles + 1) / 2;

    if (tid < CAP) sqm[tid] = (tid < m) ? sqg[c * CAP + tid] : 0.f;
    __syncthreads();

    const int wave = tid >> 6, lane = tid & 63;
    const int lr = lane & 15, q = lane >> 4;
    float hacc = 0.f, dsum = 0.f;
    const _Float16* base = gh + (size_t)c * CAP * DIM;

    // 16 waves/class cover the upper-triangle tile pairs (~21 per class).
    for (int tp = qq * 4 + wave; tp < ntp; tp += 16) {
        int ta = 0, rem = tp;
        while (rem >= ntiles - ta) { rem -= ntiles - ta; ++ta; }
        const int tb = ta + rem;
        // Pad-row data is poison but benign fp16 (no NaN/Inf); outputs gated.
        const half8* ap = (const half8*)(base + (ta * 16 + lr) * DIM + q * 8);
        const half8* bp = (const half8*)(base + (tb * 16 + lr) * DIM + q * 8);
        float4v acc = {0.f, 0.f, 0.f, 0.f};
        #pragma unroll
        for (int kb = 0; kb < 4; ++kb)        // +32 halves per K block
            acc = __builtin_amdgcn_mfma_f32_16x16x32_f16(ap[kb * 4], bp[kb * 4], acc, 0, 0, 0);
        const float w = (ta == tb) ? 1.f : 2.f;
        #pragma unroll
        for (int i = 0; i < 4; ++i) {
            const int a  = ta * 16 + q * 4 + i;   // C/D: row = quad*4 + reg
            const int bb = tb * 16 + lr;          //      col = lane & 15
            if (a < m && bb < m) {
                const float dot = acc[i];
                dsum += w * dot;                  // includes diagonal a==bb
                if (a != bb) {
                    float d = fmaxf(sqm[a] + sqm[bb] - 2.f * dot, 0.f);
                    hacc += w * fmaxf(1.f - d, 0.f);
                }
            }
        }
    }
    #pragma unroll
    for (int off = 32; off > 0; off >>= 1) {
        hacc += __shfl_xor(hacc, off);
        dsum += __shfl_xor(dsum, off);
    }
    if (lane == 0) { wred[wave] = hacc; wred[4 + wave] = dsum; }
    __syncthreads();
    if (tid == 0) {
        float h = wred[0] + wred[1] + wred[2] + wred[3];
        float d = wred[4] + wred[5] + wred[6] + wred[7];
        if (h != 0.f) atomicAdd(Hsum, h);   // hinge almost always 0 off-diag
        atomicAdd(SSsum, d);
        __threadfence();                    // release before done-count
        int p = atomicAdd(done, 1);
        lastFlag = (p == GRAMB - 1);
    }
    __syncthreads();
    if (!lastFlag) return;

    // ---------------- fused finalize (last-arriving block only) ----------
    __threadfence();                        // acquire other blocks' results
    const double Nf = (double)N_ROWS;
    double contrib = 0.0;
    if (tid < DIM)  { double v = Scol[tid]; contrib -= 2.0 * v * v; }   // -2||S||^2
    if (tid < NCLS) {
        double qv = SQc[tid];
        contrib += 2.0 * qv * (Nf - (double)cnt[tid]);  // 2N*SQ - 2 sum n_c SQ_c
    }
    if (tid == 0) {
        float H  = __hip_atomic_load(Hsum,  __ATOMIC_RELAXED, __HIP_MEMORY_SCOPE_AGENT);
        float SS = __hip_atomic_load(SSsum, __ATOMIC_RELAXED, __HIP_MEMORY_SCOPE_AGENT);
        contrib += 2.0 * (double)SS + (double)H + Nf * 1.0 /* N*margin */;
    }
    __shared__ double dred[256];
    dred[tid] = contrib;
    __syncthreads();
    for (int s = 128; s > 0; s >>= 1) {
        if (tid < s) dred[tid] += dred[tid + s];
        __syncthreads();
    }
    if (tid == 0) out[0] = (float)(dred[0] / (Nf * Nf));
}

extern "C" void kernel_launch(void* const* d_in, const int* in_sizes, int n_in,
                              void* d_out, int out_size, void* d_ws, size_t ws_size,
                              hipStream_t stream) {
    const float* x = (const float*)d_in[0];
    const int*   y = (const int*)d_in[1];

    _Float16* gh = (_Float16*)d_ws;                         // 100*224*128 fp16 = 5.73 MB
    float* sqg   = (float*)(gh + (size_t)NCLS * CAP * DIM); // 100*224
    // ---- zero region (single memset): ----
    float* Scol  = sqg + NCLS * CAP;       // 128
    float* SQc   = Scol + DIM;             // 100
    float* Hsum  = SQc + NCLS;             // 1
    float* SSsum = Hsum + 1;               // 1
    int*   cnt   = (int*)(SSsum + 1);      // 100
    int*   done  = cnt + NCLS;             // 1
    const size_t zero_words = DIM + NCLS + 2 + NCLS + 1;    // 331

    hipMemsetAsync(Scol, 0, zero_words * sizeof(float), stream);
    scan_kernel<<<SB,    256, 0, stream>>>(x, y, gh, sqg, cnt, Scol, SQc);
    gram_kernel<<<GRAMB, 256, 0, stream>>>(gh, sqg, cnt, Scol, SQc,
                                           Hsum, SSsum, done, (float*)d_out);
}

// Round 5
// 97.743 us; speedup vs baseline: 1.2721x; 1.1320x over previous
//
#include <hip/hip_runtime.h>

// ContrastiveEmbeddingLoss, N=8192, D=128, C=100, margin=1.
// loss = [ sum_{y_i!=y_j} d_ij + N*margin + sum_{same,i!=j} max(margin-d_ij,0) ] / N^2
//   dissim = 2*sum_c SQ_c*(N - n_c) - 2*||S||^2 + 2*SSsum
//     SQ_c = sum_{i in c}||x_i||^2,  S = sum_i x_i,  SSsum = sum_c sum_{a,b in c} x_a.x_b
// Only same-class pairs (~N^2/100) need explicit d -> per-class fp16 MFMA Gram.
//
// 4 graph nodes: memset(7.7KB) -> rank (LDS-histogram ranking, no dependent
// stores) -> scan (coalesced pass, placement precomputed -> full MLP) ->
// gram (800 blocks, <=1 tile-pair/wave; last block finalizes via done-counter).

#define N_ROWS 8192
#define DIM    128
#define NCLS   100
#define CAP    224            // Binom(8192,0.01): mean 82, sd 9 -> +15 sigma
#define RB     32             // rank blocks (256 rows each)
#define SCB    1024           // scan blocks (8 rows each)
#define GBPC   8              // gram blocks per class
#define GRAMB  (NCLS * GBPC)  // 800
#define NREP   8              // atomic replication for Scol/SQc

typedef _Float16 half8  __attribute__((ext_vector_type(8)));
typedef _Float16 half4v __attribute__((ext_vector_type(4)));
typedef float    float4v __attribute__((ext_vector_type(4)));

// ---------------- Kernel 0: per-row class rank, no atomic->store chains ----
__global__ __launch_bounds__(256) void rank_kernel(
    const int* __restrict__ y, int* __restrict__ cnt, int* __restrict__ rank)
{
    const int tid = threadIdx.x, r = blockIdx.x * 256 + tid;
    __shared__ int lcnt[NCLS], lbase[NCLS];
    if (tid < NCLS) lcnt[tid] = 0;
    __syncthreads();
    const int c = y[r];
    const int intra = atomicAdd(&lcnt[c], 1);        // LDS atomic (block scope)
    __syncthreads();
    if (tid < NCLS && lcnt[tid] > 0)
        lbase[tid] = atomicAdd(&cnt[tid], lcnt[tid]); // 100x32 global atomics
    __syncthreads();
    rank[r] = lbase[c] + intra;
}

// ---------------- Kernel 1: one coalesced pass over x, all stores free ------
// gh[c][rank][128] fp16 rows, sqg[c][rank], Scol8[NREP][128], SQc8[NREP][100].
__global__ __launch_bounds__(256) void scan_kernel(
    const float* __restrict__ x, const int* __restrict__ y,
    const int* __restrict__ rank,
    _Float16* __restrict__ gh, float* __restrict__ sqg,
    float* __restrict__ Scol8, float* __restrict__ SQc8)
{
    const int b = blockIdx.x, tid = threadIdx.x;
    const int l = tid & 31, g = tid >> 5;            // 32 lanes/row, 8 rows/blk
    const int r = b * 8 + g;
    const int rep = b & (NREP - 1);
    const float4* x4 = (const float4*)x;
    __shared__ float4 colred[256];

    float4 v = x4[r * 32 + l];                       // fully coalesced
    float s = v.x*v.x + v.y*v.y + v.z*v.z + v.w*v.w;
    s += __shfl_xor(s, 1);  s += __shfl_xor(s, 2);  s += __shfl_xor(s, 4);
    s += __shfl_xor(s, 8);  s += __shfl_xor(s, 16);  // row sqnorm
    const int c = y[r];                              // uniform per group
    const int p = rank[r];                           // precomputed placement
    if (p < CAP) {                                   // never false in practice
        half4v h;
        h[0] = (_Float16)v.x; h[1] = (_Float16)v.y;
        h[2] = (_Float16)v.z; h[3] = (_Float16)v.w;
        *(half4v*)(gh + (size_t)(c * CAP + p) * DIM + l * 4) = h;
        if (l == 0) sqg[c * CAP + p] = s;
    }
    if (l == 0) atomicAdd(&SQc8[rep * NCLS + c], s); // ~10-way contention

    colred[tid] = v;
    __syncthreads();
    if (tid < 32) {
        float4 a = colred[tid];
        #pragma unroll
        for (int gg = 1; gg < 8; ++gg) {
            float4 t = colred[tid + 32 * gg];
            a.x += t.x; a.y += t.y; a.z += t.z; a.w += t.w;
        }
        float* dst = Scol8 + rep * DIM;              // ~128-way contention
        atomicAdd(&dst[4 * tid + 0], a.x);
        atomicAdd(&dst[4 * tid + 1], a.y);
        atomicAdd(&dst[4 * tid + 2], a.z);
        atomicAdd(&dst[4 * tid + 3], a.w);
    }
}

// ------- Kernel 2: per-class MFMA Gram hinge (8 blocks/class) + finalize ----
__global__ __launch_bounds__(256) void gram_kernel(
    const _Float16* __restrict__ gh, const float* __restrict__ sqg,
    const int* __restrict__ cnt,
    const float* __restrict__ Scol8, const float* __restrict__ SQc8,
    float* __restrict__ Hsum, float* __restrict__ SSsum,
    int* __restrict__ done, float* __restrict__ out)
{
    const int c = blockIdx.x >> 3, qq = blockIdx.x & 7, tid = threadIdx.x;
    __shared__ float wred[8];
    __shared__ int   lastFlag;

    const int mtrue = cnt[c];
    const int m = mtrue < CAP ? mtrue : CAP;
    const int ntiles = (m + 15) >> 4;
    const int ntp = ntiles * (ntiles + 1) / 2;       // ~21 for m~82

    const int wave = tid >> 6, lane = tid & 63;
    const int lr = lane & 15, q = lane >> 4;
    float hacc = 0.f, dsum = 0.f;
    const _Float16* base = gh + (size_t)c * CAP * DIM;
    const float* sqb_ = sqg + c * CAP;

    // 32 waves/class: almost always <=1 tile-pair per wave.
    for (int tp = qq * 4 + wave; tp < ntp; tp += 32) {
        int ta = 0, rem = tp;
        while (rem >= ntiles - ta) { rem -= ntiles - ta; ++ta; }
        const int tb = ta + rem;
        // Pad rows hold benign fp16 poison (no NaN/Inf); outputs gated below.
        const half8* ap = (const half8*)(base + (ta * 16 + lr) * DIM + q * 8);
        const half8* bp = (const half8*)(base + (tb * 16 + lr) * DIM + q * 8);
        float4v acc = {0.f, 0.f, 0.f, 0.f};
        #pragma unroll
        for (int kb = 0; kb < 4; ++kb)               // +32 halves per K block
            acc = __builtin_amdgcn_mfma_f32_16x16x32_f16(ap[kb * 4], bp[kb * 4], acc, 0, 0, 0);
        const float w = (ta == tb) ? 1.f : 2.f;
        const int bb = tb * 16 + lr;                 // C/D col = lane & 15
        const float sqb = (bb < m) ? sqb_[bb] : 0.f;
        #pragma unroll
        for (int i = 0; i < 4; ++i) {
            const int a = ta * 16 + q * 4 + i;       // C/D row = quad*4 + reg
            if (a < m && bb < m) {
                const float dot = acc[i];
                dsum += w * dot;                     // includes diagonal a==bb
                if (a != bb) {
                    float d = fmaxf(sqb_[a] + sqb - 2.f * dot, 0.f);
                    hacc += w * fmaxf(1.f - d, 0.f);
                }
            }
        }
    }
    #pragma unroll
    for (int off = 32; off > 0; off >>= 1) {
        hacc += __shfl_xor(hacc, off);
        dsum += __shfl_xor(dsum, off);
    }
    if (lane == 0) { wred[wave] = hacc; wred[4 + wave] = dsum; }
    __syncthreads();
    if (tid == 0) {
        float h = wred[0] + wred[1] + wred[2] + wred[3];
        float d = wred[4] + wred[5] + wred[6] + wred[7];
        if (h != 0.f) atomicAdd(Hsum, h);
        if (d != 0.f) atomicAdd(SSsum, d);
        __threadfence();                             // release before counting
        int p = atomicAdd(done, 1);
        lastFlag = (p == GRAMB - 1);
    }
    __syncthreads();
    if (!lastFlag) return;

    // ---------------- fused finalize (last-arriving block only) ------------
    __threadfence();                                 // acquire others' results
    const double Nf = (double)N_ROWS;
    double contrib = 0.0;
    if (tid < DIM) {                                 // -2 ||S||^2
        float sc = 0.f;
        #pragma unroll
        for (int k = 0; k < NREP; ++k) sc += Scol8[k * DIM + tid];
        contrib -= 2.0 * (double)sc * (double)sc;
    }
    if (tid < NCLS) {                                // 2 SQ_c (N - n_c)
        float qv = 0.f;
        #pragma unroll
        for (int k = 0; k < NREP; ++k) qv += SQc8[k * NCLS + tid];
        contrib += 2.0 * (double)qv * (Nf - (double)cnt[tid]);
    }
    if (tid == 0) {
        float H  = __hip_atomic_load(Hsum,  __ATOMIC_RELAXED, __HIP_MEMORY_SCOPE_AGENT);
        float SS = __hip_atomic_load(SSsum, __ATOMIC_RELAXED, __HIP_MEMORY_SCOPE_AGENT);
        contrib += 2.0 * (double)SS + (double)H + Nf * 1.0 /* N*margin */;
    }
    __shared__ double dred[256];
    dred[tid] = contrib;
    __syncthreads();
    for (int s = 128; s > 0; s >>= 1) {
        if (tid < s) dred[tid] += dred[tid + s];
        __syncthreads();
    }
    if (tid == 0) out[0] = (float)(dred[0] / (Nf * Nf));
}

extern "C" void kernel_launch(void* const* d_in, const int* in_sizes, int n_in,
                              void* d_out, int out_size, void* d_ws, size_t ws_size,
                              hipStream_t stream) {
    const float* x = (const float*)d_in[0];
    const int*   y = (const int*)d_in[1];

    _Float16* gh = (_Float16*)d_ws;                         // 100*224*128 fp16 = 5.73 MB
    float* sqg   = (float*)(gh + (size_t)NCLS * CAP * DIM); // 100*224
    int*   rank  = (int*)(sqg + NCLS * CAP);                // 8192
    // ---- zero region (single small memset): ----
    float* Scol8 = (float*)(rank + N_ROWS);  // NREP*128
    float* SQc8  = Scol8 + NREP * DIM;       // NREP*100
    float* Hsum  = SQc8 + NREP * NCLS;       // 1
    float* SSsum = Hsum + 1;                 // 1
    int*   cnt   = (int*)(SSsum + 1);        // 100
    int*   done  = cnt + NCLS;               // 1
    const size_t zero_words = NREP * DIM + NREP * NCLS + 2 + NCLS + 1; // 1927

    hipMemsetAsync(Scol8, 0, zero_words * sizeof(float), stream);
    rank_kernel<<<RB,    256, 0, stream>>>(y, cnt, rank);
    scan_kernel<<<SCB,   256, 0, stream>>>(x, y, rank, gh, sqg, Scol8, SQc8);
    gram_kernel<<<GRAMB, 256, 0, stream>>>(gh, sqg, cnt, Scol8, SQc8,
                                           Hsum, SSsum, done, (float*)d_out);
}